// Round 9
// baseline (36.860 us; speedup 1.0000x reference)
//
#include <hip/hip_runtime.h>
#include <hip/hip_fp16.h>

// Problem constants (from reference)
#define BSZ     1024   // batch
#define N_IN    1024
#define NLAYERS 5
#define NPL     2048   // nodes per layer
#define FANIN   16
#define N_OUT   256

#define VALS_ROWS   (N_IN + 4 * NPL)            // 9216 gatherable rows (L0..L3)
#define CPB         4                           // batch columns per block
#define NBLK        (BSZ / CPB)                 // 256 blocks
#define ROW_B       8                           // 4 cols x fp16 per row
#define LDS_BYTES   (VALS_ROWS * ROW_B)         // 73728 B
#define L3_BASE     (N_IN + 3 * NPL)            // 7168: first layer-3 row

// d_ws layout (u32 units)
#define PK012_OFF   0                           // [3*NPL][16]
#define PK3C_OFF    98304                       // [<=NPL][16] compacted layer 3
#define PK4_OFF     131072                      // [N_OUT][16]
#define LIST3_OFF   135168                      // [<=NPL] alive layer-3 node ids
#define CNT3_OFF    137216                      // 1 u32
#define BIAS3C_OFF  137248                      // [<=NPL] f32

union H4 { unsigned long long u; __half2 h2[2]; };

__device__ __forceinline__ float fast_tanh(float x) {
    float t = __expf(2.0f * x);
    return 1.0f - 2.0f / (t + 1.0f);
}
__device__ __forceinline__ float fast_sigmoid(float x) {
    return 1.0f / (1.0f + __expf(-x));
}

// ---------------------------------------------------------------------------
// Prep kernel, 25 blocks x 1024 threads.
// Block 0 (heavy, dispatched first): pack layer-4's used 256 nodes; build
//   layer-3 liveness flags from their 4096 indices; ballot-based two-level
//   prefix sum (16 waves x 64-bit ballots -> 32 chunk totals -> 32-lane scan)
//   -> compacted list/pk/bias for layer 3. ~3 barriers total.
// Blocks 1..24 (256 active threads each): pack layers 0..2 (6144 nodes) as
//   val = ((idx*8) << 16) | fp16(w), per-node bank-sorted (key = idx&15, the
//   ds_read_b64 bank-pair) and rotated by n for near-uniform wave bank spread.
// ---------------------------------------------------------------------------
__global__ __launch_bounds__(1024) void prep_kernel(
    const int* __restrict__ src, const float* __restrict__ wsrc,
    const float* __restrict__ biases, unsigned int* __restrict__ ws)
{
    const int tid = threadIdx.x;

    if (blockIdx.x != 0) {
        if (tid >= 256) return;
        const int t = (blockIdx.x - 1) * 256 + tid;   // node index l*NPL+n, l<3
        const int n = t & (NPL - 1);
        const int*   s  = src  + (size_t)t * FANIN;
        const float* ww = wsrc + (size_t)t * FANIN;

        int          key[FANIN];
        unsigned int val[FANIN];
#pragma unroll
        for (int f = 0; f < FANIN; ++f) {
            unsigned int idx = (unsigned int)s[f];
            key[f] = (int)(idx & 15u);
            unsigned short hw = __half_as_ushort(__float2half(ww[f]));
            val[f] = ((idx << 3) << 16) | (unsigned int)hw;
        }
        unsigned int* dst = ws + PK012_OFF + (size_t)t * FANIN;
#pragma unroll
        for (int f = 0; f < FANIN; ++f) {
            int rank = 0;
#pragma unroll
            for (int g = 0; g < FANIN; ++g)
                rank += (key[g] < key[f]) || (key[g] == key[f] && g < f);
            dst[(rank - n) & 15] = val[f];
        }
        return;
    }

    // ---- block 0: layer-4 pack + layer-3 liveness/compaction ----
    __shared__ unsigned int flags[NPL];         // 8 KB
    __shared__ unsigned int chunk_tot[32];
    __shared__ unsigned int chunk_excl[32];
    flags[tid] = 0u; flags[tid + 1024] = 0u;
    __syncthreads();

    const int base4 = (4 * NPL + (NPL - N_OUT)) * FANIN;  // first used L4 edge
#pragma unroll
    for (int e = tid; e < N_OUT * FANIN; e += 1024) {     // 4 iterations
        unsigned int idx = (unsigned int)src[base4 + e];
        unsigned short hw = __half_as_ushort(__float2half(wsrc[base4 + e]));
        ws[PK4_OFF + e] = (idx << 16) | (unsigned int)hw;
        if (idx >= (unsigned)L3_BASE) flags[idx - L3_BASE] = 1u;  // benign race
    }
    __syncthreads();

    // two-level ballot scan: wave w owns chunks w and w+16 (64 nodes each)
    const int lane = tid & 63;
    const int wv   = tid >> 6;
    const int n0 = wv * 64 + lane;
    const int n1 = (wv + 16) * 64 + lane;
    const unsigned long long m0 = __ballot(flags[n0] != 0u);
    const unsigned long long m1 = __ballot(flags[n1] != 0u);
    if (lane == 0) {
        chunk_tot[wv]      = (unsigned int)__popcll(m0);
        chunk_tot[wv + 16] = (unsigned int)__popcll(m1);
    }
    __syncthreads();
    if (tid < 32) {
        unsigned int s = 0;
        for (int i = 0; i < 32; ++i) s += (i < tid) ? chunk_tot[i] : 0u;
        chunk_excl[tid] = s;
        if (tid == 31) ws[CNT3_OFF] = s + chunk_tot[31];
    }
    __syncthreads();

    const unsigned long long below = (1ull << lane) - 1ull;
    const unsigned int p0 = chunk_excl[wv]      + (unsigned int)__popcll(m0 & below);
    const unsigned int p1 = chunk_excl[wv + 16] + (unsigned int)__popcll(m1 & below);

#pragma unroll
    for (int k = 0; k < 2; ++k) {
        const int nn = k ? n1 : n0;
        const unsigned int pos = k ? p1 : p0;
        if (flags[nn]) {
            ws[LIST3_OFF + pos] = (unsigned int)nn;
            ((float*)ws)[BIAS3C_OFF + pos] = biases[(size_t)3 * NPL + nn];
            const int t3 = (3 * NPL + nn) * FANIN;
#pragma unroll
            for (int f = 0; f < FANIN; ++f) {
                unsigned int idx = (unsigned int)src[t3 + f];
                unsigned short hw = __half_as_ushort(__float2half(wsrc[t3 + f]));
                ws[PK3C_OFF + (size_t)pos * FANIN + ((f + pos) & 15)] =
                    ((idx << 3) << 16) | (unsigned int)hw;
            }
        }
    }
}

// ---------------------------------------------------------------------------
// One node's gather + tanh + LDS row write. pk indices are compile-time after
// inlining+unroll (no scratch). off is a pre-shifted byte offset in hi16.
// ---------------------------------------------------------------------------
__device__ __forceinline__ void node_tanh(
    const unsigned int* pk, float bv, int row, char* lds)
{
    float a0 = bv, a1 = bv, a2 = bv, a3 = bv;
#pragma unroll
    for (int f = 0; f < FANIN; ++f) {
        const unsigned int u   = pk[f];
        const unsigned int off = u >> 16;
        H4 v;
        v.u = *reinterpret_cast<const unsigned long long*>(lds + off);
        const float wf = __half2float(
            __ushort_as_half((unsigned short)(u & 0xffffu)));
        a0 = fmaf(__half2float(v.h2[0].x), wf, a0);
        a1 = fmaf(__half2float(v.h2[0].y), wf, a1);
        a2 = fmaf(__half2float(v.h2[1].x), wf, a2);
        a3 = fmaf(__half2float(v.h2[1].y), wf, a3);
    }
    a0 = fast_tanh(a0); a1 = fast_tanh(a1);
    a2 = fast_tanh(a2); a3 = fast_tanh(a3);
    H4 rec;
    rec.h2[0] = __halves2half2(__float2half(a0), __float2half(a1));
    rec.h2[1] = __halves2half2(__float2half(a2), __float2half(a3));
    *reinterpret_cast<unsigned long long*>(lds + (size_t)row * ROW_B) = rec.u;
}

// ---------------------------------------------------------------------------
// Fused whole-network kernel. Each block owns 4 batch columns; all activations
// in LDS as 8-B rows; gathers are single ds_read_b64. pk double-buffered
// (pkA/pkB) and prefetched ahead of dependent compute. Layer 3 runs only over
// the compacted alive-node list (cnt3 of 2048); dead LDS rows are never read.
// ---------------------------------------------------------------------------
__global__ __launch_bounds__(1024) void fused_net_kernel(
    const float* __restrict__ inputs,           // (BSZ, N_IN) f32
    const unsigned int* __restrict__ ws,        // prep output
    const float* __restrict__ biases,           // (L, NPL) f32
    float* __restrict__ out)                    // (BSZ, N_OUT) f32
{
    extern __shared__ char lds[];
    const int tid = threadIdx.x;
    const int c0  = blockIdx.x * CPB;
    const unsigned int* pk012 = ws + PK012_OFF;
    const unsigned int* pk3c  = ws + PK3C_OFF;
    const unsigned int* pk4   = ws + PK4_OFF;
    const unsigned int* list3 = ws + LIST3_OFF;
    const float* bias3c = (const float*)(ws + BIAS3C_OFF);
    const int cnt3 = (int)ws[CNT3_OFF];         // uniform scalar load

    // ---- stage 4 input columns as one 8-B row record per node ----
    {
        float v0 = inputs[(size_t)(c0 + 0) * N_IN + tid];
        float v1 = inputs[(size_t)(c0 + 1) * N_IN + tid];
        float v2 = inputs[(size_t)(c0 + 2) * N_IN + tid];
        float v3 = inputs[(size_t)(c0 + 3) * N_IN + tid];
        H4 rec;
        rec.h2[0] = __halves2half2(__float2half(v0), __float2half(v1));
        rec.h2[1] = __halves2half2(__float2half(v2), __float2half(v3));
        *reinterpret_cast<unsigned long long*>(lds + (size_t)tid * ROW_B) = rec.u;
    }
    __syncthreads();

    unsigned int pkA[FANIN], pkB[FANIN];
    int   n3a = 0, n3b = 0;
    float b3a = 0.f, b3b = 0.f;

#pragma unroll
    for (int f = 0; f < FANIN; ++f)
        pkA[f] = pk012[(size_t)tid * FANIN + f];

    // ---- layers 0..2: full 2048 nodes, 2 sweeps, tanh ----
    for (int l = 0; l < 3; ++l) {
        const float* bl = biases + (size_t)l * NPL;
        const int wbase = N_IN + l * NPL;

#pragma unroll
        for (int f = 0; f < FANIN; ++f)
            pkB[f] = pk012[((size_t)l * NPL + 1024 + tid) * FANIN + f];

        node_tanh(pkA, bl[tid], wbase + tid, lds);

        if (l < 2) {
#pragma unroll
            for (int f = 0; f < FANIN; ++f)
                pkA[f] = pk012[((size_t)(l + 1) * NPL + tid) * FANIN + f];
        } else if (tid < cnt3) {                // prefetch layer-3 sweep 0
            n3a = (int)list3[tid];
            b3a = bias3c[tid];
#pragma unroll
            for (int f = 0; f < FANIN; ++f)
                pkA[f] = pk3c[(size_t)tid * FANIN + f];
        }

        node_tanh(pkB, bl[1024 + tid], wbase + 1024 + tid, lds);
        __syncthreads();
    }

    // ---- layer 3: compacted alive nodes only ----
    {
        const int i1 = 1024 + tid;
        if (i1 < cnt3) {                        // prefetch sweep 1
            n3b = (int)list3[i1];
            b3b = bias3c[i1];
#pragma unroll
            for (int f = 0; f < FANIN; ++f)
                pkB[f] = pk3c[(size_t)i1 * FANIN + f];
        }
        if (tid < cnt3)
            node_tanh(pkA, b3a, L3_BASE + n3a, lds);

        if (tid < N_OUT) {                      // prefetch layer-4 pk -> pkA
#pragma unroll
            for (int f = 0; f < FANIN; ++f)
                pkA[f] = pk4[(size_t)tid * FANIN + f];
        }
        if (i1 < cnt3)
            node_tanh(pkB, b3b, L3_BASE + n3b, lds);
        __syncthreads();
    }

    // ---- layer 4: last N_OUT nodes only; sigmoid; f32 out ----
    if (tid < N_OUT) {
        const float bv = biases[(size_t)4 * NPL + (NPL - N_OUT) + tid];
        float a0 = bv, a1 = bv, a2 = bv, a3 = bv;
#pragma unroll
        for (int f = 0; f < FANIN; ++f) {
            const unsigned int u   = pkA[f];
            const unsigned int off = (u >> 16) << 3;    // raw idx -> byte off
            H4 v;
            v.u = *reinterpret_cast<const unsigned long long*>(lds + off);
            const float wf = __half2float(
                __ushort_as_half((unsigned short)(u & 0xffffu)));
            a0 = fmaf(__half2float(v.h2[0].x), wf, a0);
            a1 = fmaf(__half2float(v.h2[0].y), wf, a1);
            a2 = fmaf(__half2float(v.h2[1].x), wf, a2);
            a3 = fmaf(__half2float(v.h2[1].y), wf, a3);
        }
        a0 = fast_sigmoid(a0); a1 = fast_sigmoid(a1);
        a2 = fast_sigmoid(a2); a3 = fast_sigmoid(a3);
        const int j = tid;
        out[(size_t)(c0 + 0) * N_OUT + j] = a0;
        out[(size_t)(c0 + 1) * N_OUT + j] = a1;
        out[(size_t)(c0 + 2) * N_OUT + j] = a2;
        out[(size_t)(c0 + 3) * N_OUT + j] = a3;
    }
}

// ---------------------------------------------------------------------------
// Launch: prep (pack + ballot-scan layer-3 compaction) then one fused kernel.
// ---------------------------------------------------------------------------
extern "C" void kernel_launch(void* const* d_in, const int* in_sizes, int n_in,
                              void* d_out, int out_size, void* d_ws, size_t ws_size,
                              hipStream_t stream)
{
    const float* inputs   = (const float*)d_in[0];
    const int*   edge_src = (const int*)  d_in[1];
    const float* edge_w   = (const float*)d_in[2];
    const float* biases   = (const float*)d_in[3];
    float* out = (float*)d_out;
    unsigned int* ws = (unsigned int*)d_ws;     // ~557 KB used

    prep_kernel<<<25, 1024, 0, stream>>>(edge_src, edge_w, biases, ws);

    fused_net_kernel<<<NBLK, 1024, LDS_BYTES, stream>>>(
        inputs, ws, biases, out);
}

// Round 10
// 26.314 us; speedup vs baseline: 1.4008x; 1.4008x over previous
//
#include <hip/hip_runtime.h>
#include <hip/hip_fp16.h>

// Problem constants (from reference)
#define BSZ     1024   // batch
#define N_IN    1024
#define NLAYERS 5
#define NPL     2048   // nodes per layer
#define FANIN   16
#define N_OUT   256

#define VALS_ROWS   (N_IN + 4 * NPL)            // 9216 gatherable rows
#define CPB         4                           // batch columns per block
#define NBLK        (BSZ / CPB)                 // 256 blocks
#define ROW_B       8                           // 4 cols x fp16 per row
#define LDS_BYTES   (VALS_ROWS * ROW_B)         // 73728 B

union H4 { unsigned long long u; __half2 h2[2]; };

// ---------------------------------------------------------------------------
// Pack kernel (r7 structure). Layout [l*NPL+n][FANIN]; per-node bank-sort by
// ds_read_b64 bank-pair (idx & 15), rotated by n so each gather step presents
// near-uniform banks across a wave. val = (off_hi << 16) | fp16(w);
// off_hi = idx*8 (byte offset) for tanh layers, raw idx for the final layer.
// ---------------------------------------------------------------------------
__global__ __launch_bounds__(256) void pack_edges_kernel(
    const int* __restrict__ src, const float* __restrict__ wsrc,
    unsigned int* __restrict__ packed)
{
    int t = blockIdx.x * 256 + threadIdx.x;      // one (l, n) pair per thread
    if (t >= NLAYERS * NPL) return;
    const int l = t / NPL;
    const int n = t - l * NPL;
    const int*   s  = src  + (size_t)t * FANIN;
    const float* ww = wsrc + (size_t)t * FANIN;

    int          key[FANIN];
    unsigned int val[FANIN];
#pragma unroll
    for (int f = 0; f < FANIN; ++f) {
        unsigned int idx = (unsigned int)s[f];
        key[f] = (int)(idx & 15u);                       // bank-pair of ds_read_b64
        unsigned int hi = (l < NLAYERS - 1) ? (idx << 3) // pre-shifted byte offset
                                            : idx;       // final layer: raw idx
        unsigned short hw = __half_as_ushort(__float2half(ww[f]));
        val[f] = (hi << 16) | (unsigned int)hw;
    }

    unsigned int* dst = packed + (size_t)t * FANIN;
#pragma unroll
    for (int f = 0; f < FANIN; ++f) {
        int rank = 0;
#pragma unroll
        for (int g = 0; g < FANIN; ++g)
            rank += (key[g] < key[f]) || (key[g] == key[f] && g < f);
        dst[(rank - n) & 15] = val[f];                   // rotated sorted order
    }
}

// ---------------------------------------------------------------------------
// One node: 16 x {ds_read_b64 gather, 2 x v_pk_fma_f16}, f32 tanh, LDS write.
// f16 packed accumulation: ~4 VALU/edge (vs ~8-10 with f32 mix path) and
// -14 VGPRs -> stays clear of the 128-VGPR cap for 1024-thread blocks.
// ---------------------------------------------------------------------------
__device__ __forceinline__ float fast_tanh(float x) {
    float t = __expf(2.0f * x);
    return 1.0f - 2.0f / (t + 1.0f);
}
__device__ __forceinline__ float fast_sigmoid(float x) {
    return 1.0f / (1.0f + __expf(-x));
}

__device__ __forceinline__ void node_tanh(
    const unsigned int* pk, float bvf, int row, char* lds)
{
    const __half hb = __float2half(bvf);
    __half2 a01 = __halves2half2(hb, hb);
    __half2 a23 = a01;
#pragma unroll
    for (int f = 0; f < FANIN; ++f) {
        const unsigned int u   = pk[f];
        const unsigned int off = u >> 16;                // pre-shifted byte off
        H4 v;
        v.u = *reinterpret_cast<const unsigned long long*>(lds + off);
        const __half2 w2 = __half2half2(
            __ushort_as_half((unsigned short)(u & 0xffffu)));
        a01 = __hfma2(v.h2[0], w2, a01);                 // v_pk_fma_f16
        a23 = __hfma2(v.h2[1], w2, a23);
    }
    float a0 = fast_tanh(__half2float(__low2half(a01)));
    float a1 = fast_tanh(__half2float(__high2half(a01)));
    float a2 = fast_tanh(__half2float(__low2half(a23)));
    float a3 = fast_tanh(__half2float(__high2half(a23)));
    H4 rec;
    rec.h2[0] = __halves2half2(__float2half(a0), __float2half(a1));
    rec.h2[1] = __halves2half2(__float2half(a2), __float2half(a3));
    *reinterpret_cast<unsigned long long*>(lds + (size_t)row * ROW_B) = rec.u;
}

// ---------------------------------------------------------------------------
// Fused whole-network kernel (r7 structure). Each block owns 4 batch columns;
// all activations in LDS as 8-B rows; gathers are single ds_read_b64 with the
// bank-balanced schedule. pk double-buffered (pkA/pkB), prefetched ahead of
// dependent compute and before the layer barrier.
// ---------------------------------------------------------------------------
__global__ __launch_bounds__(1024) void fused_net_kernel(
    const float* __restrict__ inputs,           // (BSZ, N_IN) f32
    const unsigned int* __restrict__ packed,    // [l*NPL+n][FANIN]
    const float* __restrict__ biases,           // (L, NPL) f32
    float* __restrict__ out)                    // (BSZ, N_OUT) f32
{
    extern __shared__ char lds[];
    const int tid = threadIdx.x;
    const int c0  = blockIdx.x * CPB;           // batch base for this block

    // ---- stage 4 input columns as one 8-B row record per node ----
    {
        float v0 = inputs[(size_t)(c0 + 0) * N_IN + tid];
        float v1 = inputs[(size_t)(c0 + 1) * N_IN + tid];
        float v2 = inputs[(size_t)(c0 + 2) * N_IN + tid];
        float v3 = inputs[(size_t)(c0 + 3) * N_IN + tid];
        H4 rec;
        rec.h2[0] = __halves2half2(__float2half(v0), __float2half(v1));
        rec.h2[1] = __halves2half2(__float2half(v2), __float2half(v3));
        *reinterpret_cast<unsigned long long*>(lds + (size_t)tid * ROW_B) = rec.u;
    }
    __syncthreads();

    unsigned int pkA[FANIN], pkB[FANIN];

    // preload layer 0, sweep 0
#pragma unroll
    for (int f = 0; f < FANIN; ++f)
        pkA[f] = packed[(size_t)tid * FANIN + f];

    for (int l = 0; l < NLAYERS - 1; ++l) {
        const float* bl = biases + (size_t)l * NPL;
        const int wbase = N_IN + l * NPL;

        // issue sweep-1 pk loads before sweep-0 compute
#pragma unroll
        for (int f = 0; f < FANIN; ++f)
            pkB[f] = packed[((size_t)l * NPL + 1024 + tid) * FANIN + f];

        node_tanh(pkA, bl[tid], wbase + tid, lds);

        // issue NEXT-layer sweep-0 pk loads (or final-layer pk) before the
        // barrier: latency hides under sweep-1 compute + barrier drain
        if (l < NLAYERS - 2) {
#pragma unroll
            for (int f = 0; f < FANIN; ++f)
                pkA[f] = packed[((size_t)(l + 1) * NPL + tid) * FANIN + f];
        } else if (tid < N_OUT) {
            const int n4 = NPL - N_OUT + tid;
#pragma unroll
            for (int f = 0; f < FANIN; ++f)
                pkA[f] = packed[((size_t)(NLAYERS - 1) * NPL + n4) * FANIN + f];
        }

        node_tanh(pkB, bl[1024 + tid], wbase + 1024 + tid, lds);
        __syncthreads();
    }

    // ---- layer 4: last N_OUT nodes only; sigmoid; f32 accum; f32 out ----
    if (tid < N_OUT) {
        const int n = NPL - N_OUT + tid;
        const float bv = biases[(size_t)(NLAYERS - 1) * NPL + n];
        float a0 = bv, a1 = bv, a2 = bv, a3 = bv;
#pragma unroll
        for (int f = 0; f < FANIN; ++f) {
            const unsigned int u   = pkA[f];
            const unsigned int off = (u >> 16) << 3;     // raw idx -> byte off
            H4 v;
            v.u = *reinterpret_cast<const unsigned long long*>(lds + off);
            const float wf = __half2float(
                __ushort_as_half((unsigned short)(u & 0xffffu)));
            a0 = fmaf(__half2float(v.h2[0].x), wf, a0);
            a1 = fmaf(__half2float(v.h2[0].y), wf, a1);
            a2 = fmaf(__half2float(v.h2[1].x), wf, a2);
            a3 = fmaf(__half2float(v.h2[1].y), wf, a3);
        }
        a0 = fast_sigmoid(a0); a1 = fast_sigmoid(a1);
        a2 = fast_sigmoid(a2); a3 = fast_sigmoid(a3);
        const int j = tid;                               // output column
        out[(size_t)(c0 + 0) * N_OUT + j] = a0;
        out[(size_t)(c0 + 1) * N_OUT + j] = a1;
        out[(size_t)(c0 + 2) * N_OUT + j] = a2;
        out[(size_t)(c0 + 3) * N_OUT + j] = a3;
    }
}

// ---------------------------------------------------------------------------
// Launch: pack (sort+rotate) edges into d_ws (0.66 MB), then one fused kernel.
// 256 blocks x 1024 threads, 73728 B dynamic LDS per block.
// ---------------------------------------------------------------------------
extern "C" void kernel_launch(void* const* d_in, const int* in_sizes, int n_in,
                              void* d_out, int out_size, void* d_ws, size_t ws_size,
                              hipStream_t stream)
{
    const float* inputs   = (const float*)d_in[0];
    const int*   edge_src = (const int*)  d_in[1];
    const float* edge_w   = (const float*)d_in[2];
    const float* biases   = (const float*)d_in[3];
    float* out = (float*)d_out;
    unsigned int* packed = (unsigned int*)d_ws;   // L*NPL*FANIN*4 B = 655,360 B

    pack_edges_kernel<<<(NLAYERS * NPL + 255) / 256, 256, 0, stream>>>(
        edge_src, edge_w, packed);

    fused_net_kernel<<<NBLK, 1024, LDS_BYTES, stream>>>(
        inputs, packed, biases, out);
}